// Round 8
// baseline (77.183 us; speedup 1.0000x reference)
//
#include <hip/hip_runtime.h>

#define BB 4
#define SS 4096
#define EE 128
#define CNT_TARGET 65   // 64 vpart blocks + 1 special block per batch

typedef __attribute__((ext_vector_type(8))) short bf16x8;
typedef __attribute__((ext_vector_type(4))) float f32x4;

__device__ __forceinline__ unsigned short f2bf(float f) {
    unsigned u = __float_as_uint(f);
    u = (u + 0x7FFFu + ((u >> 16) & 1u)) >> 16;
    return (unsigned short)u;
}
__device__ __forceinline__ float bf2f(unsigned short h) {
    return __uint_as_float(((unsigned)h) << 16);
}
// split from memory (global/LDS) via float4 vector loads
__device__ __forceinline__ void split8(const float* p, bf16x8& h, bf16x8& l) {
    float4 v0 = *reinterpret_cast<const float4*>(p);
    float4 v1 = *reinterpret_cast<const float4*>(p + 4);
    float f[8] = {v0.x, v0.y, v0.z, v0.w, v1.x, v1.y, v1.z, v1.w};
    #pragma unroll
    for (int i = 0; i < 8; ++i) {
        unsigned short hb = f2bf(f[i]);
        h[i] = (short)hb;
        l[i] = (short)f2bf(f[i] - bf2f(hb));
    }
}
// split from a register array (constant-indexed after unroll -> stays in VGPRs)
__device__ __forceinline__ void split8r(const float* f, bf16x8& h, bf16x8& l) {
    #pragma unroll
    for (int i = 0; i < 8; ++i) {
        unsigned short hb = f2bf(f[i]);
        h[i] = (short)hb;
        l[i] = (short)f2bf(f[i] - bf2f(hb));
    }
}
// 3-product split-bf16 MFMA: ~f32 accuracy (drops lo*lo)
__device__ __forceinline__ f32x4 mfma3(bf16x8 ah, bf16x8 al, bf16x8 bh, bf16x8 bl, f32x4 c) {
    c = __builtin_amdgcn_mfma_f32_16x16x32_bf16(ah, bh, c, 0, 0, 0);
    c = __builtin_amdgcn_mfma_f32_16x16x32_bf16(al, bh, c, 0, 0, 0);
    c = __builtin_amdgcn_mfma_f32_16x16x32_bf16(ah, bl, c, 0, 0, 0);
    return c;
}

// ---------------------------------------------------------------------------
// Single fused kernel. blockIdx.x:
//   [0,4):    special producer, batch b=bx. 4 waves, wave w owns t-strip
//             [16w,16w+16). K-GEMM -> masked ksub (LDS, f32) -> barrier ->
//             Mt-GEMM D[e][t] (A=WqT via strided regs, B=ksub rows) ->
//             Mth/Mtl[t][e] bf16 hi/lo; V-GEMM -> Vt[v][t] bf16.
//   [4,260):  vpart producer: idx=bx-4, b=idx>>6, i=idx&63:
//             chunk-colsum of x[b, 64+63i .. +63, :] projected through Wv.
//   [260,516): consumer: cb=bx-260, b=cb>>6, 64 rows at s0=(cb&63)*64.
//             x frags -> spin on cnt[b]==65 -> block-shared vsum ->
//             S=x@Mt (split MFMA) -> softmax(+4032 zero cols) -> P@V -> out.
// Sync: producers __threadfence + release fetch_add(cnt[b]); consumers
// relaxed-poll + acquire. cnt zeroed by a hipMemsetAsync node each call.
// ---------------------------------------------------------------------------
__global__ __launch_bounds__(256, 2)
void fused_all(const float* __restrict__ x, const float* __restrict__ Wk,
               const float* __restrict__ Wq, const float* __restrict__ Wv,
               int* cnt, float* vpart,
               unsigned short* __restrict__ Mth, unsigned short* __restrict__ Mtl,
               unsigned short* __restrict__ Vt, float* __restrict__ out)
{
    __shared__ __align__(16) char smem[18944];
    const int tid = threadIdx.x;
    const int bx = blockIdx.x;

    if (bx < 4) {
        // ================== special producer (batch b = bx) ==================
        const int b = bx;
        float (*ksub)[68] = reinterpret_cast<float (*)[68]>(smem);  // [t][j]
        const int l = tid & 63, w = tid >> 6;
        const int lm = l & 15, lg = l >> 4;
        const int t0 = w * 16;

        // WqT A-frag raw loads (needed after barrier; issue early to hide):
        // wq_raw[eti][kt2][i] = Wq[kt2*32+lg*8+i][32w+16*eti+lm]
        float wq_raw[2][2][8];
        #pragma unroll
        for (int eti = 0; eti < 2; ++eti)
            #pragma unroll
            for (int kt2 = 0; kt2 < 2; ++kt2) {
                const int e = 32 * w + 16 * eti + lm;
                const int j0 = kt2 * 32 + lg * 8;
                #pragma unroll
                for (int i = 0; i < 8; ++i)
                    wq_raw[eti][kt2][i] = Wq[(size_t)(j0 + i) * EE + e];
            }

        // x A-frags for this t-strip (shared by K and V GEMMs)
        bf16x8 xh[4], xl[4];
        const float* xrow = x + ((size_t)b * SS + t0 + lm) * EE + lg * 8;
        #pragma unroll
        for (int kt = 0; kt < 4; ++kt)
            split8(xrow + kt * 32, xh[kt], xl[kt]);

        // K-GEMM: K[t][j] = x64[t].Wk[j]; mask t<=j; write own strip to ksub
        #pragma unroll
        for (int jt = 0; jt < 4; ++jt) {
            f32x4 a = {0.f, 0.f, 0.f, 0.f};
            const float* wkr = Wk + (size_t)(jt * 16 + lm) * EE + lg * 8;
            #pragma unroll
            for (int kt = 0; kt < 4; ++kt) {
                bf16x8 bh, bl;
                split8(wkr + kt * 32, bh, bl);
                a = mfma3(xh[kt], xl[kt], bh, bl, a);
            }
            const int j = jt * 16 + lm;
            #pragma unroll
            for (int r = 0; r < 4; ++r) {
                const int t = t0 + lg * 4 + r;
                ksub[t][j] = (t <= j) ? a[r] : 0.f;
            }
        }
        __syncthreads();                       // full ksub visible

        // Mt-GEMM: D[e][t] = sum_j Wq[j][e]*ksub[t][j]; wave owns e in [32w,32w+32)
        bf16x8 ah[2][2], al[2][2];
        #pragma unroll
        for (int eti = 0; eti < 2; ++eti)
            #pragma unroll
            for (int kt2 = 0; kt2 < 2; ++kt2)
                split8r(&wq_raw[eti][kt2][0], ah[eti][kt2], al[eti][kt2]);
        #pragma unroll
        for (int eti = 0; eti < 2; ++eti)
            #pragma unroll
            for (int tt = 0; tt < 4; ++tt) {
                f32x4 a = {0.f, 0.f, 0.f, 0.f};
                #pragma unroll
                for (int kt2 = 0; kt2 < 2; ++kt2) {
                    bf16x8 bh, bl;
                    split8(&ksub[tt * 16 + lm][kt2 * 32 + lg * 8], bh, bl);
                    a = mfma3(ah[eti][kt2], al[eti][kt2], bh, bl, a);
                }
                const int t = tt * 16 + lm;
                const int e0 = 32 * w + 16 * eti + lg * 4;
                unsigned short h0 = f2bf(a[0]), h1 = f2bf(a[1]);
                unsigned short h2 = f2bf(a[2]), h3 = f2bf(a[3]);
                ushort4 hv = make_ushort4(h0, h1, h2, h3);
                ushort4 lv = make_ushort4(f2bf(a[0] - bf2f(h0)), f2bf(a[1] - bf2f(h1)),
                                          f2bf(a[2] - bf2f(h2)), f2bf(a[3] - bf2f(h3)));
                const size_t off = (size_t)b * 8192 + (size_t)t * 128 + e0;
                *reinterpret_cast<ushort4*>(Mth + off) = hv;
                *reinterpret_cast<ushort4*>(Mtl + off) = lv;
            }

        // V-GEMM: V[t][v] = x64[t].Wv[v]; store Vt[v][t] bf16 (t-consecutive)
        #pragma unroll
        for (int vt = 0; vt < 8; ++vt) {
            f32x4 a = {0.f, 0.f, 0.f, 0.f};
            const float* wvr = Wv + (size_t)(vt * 16 + lm) * EE + lg * 8;
            #pragma unroll
            for (int kt = 0; kt < 4; ++kt) {
                bf16x8 bh, bl;
                split8(wvr + kt * 32, bh, bl);
                a = mfma3(xh[kt], xl[kt], bh, bl, a);
            }
            const int v = vt * 16 + lm;
            ushort4 pk = make_ushort4(f2bf(a[0]), f2bf(a[1]), f2bf(a[2]), f2bf(a[3]));
            *reinterpret_cast<ushort4*>(Vt + (size_t)b * 8192 + (size_t)v * 64 + t0 + lg * 4) = pk;
        }

        __threadfence();
        __syncthreads();
        if (tid == 0)
            __hip_atomic_fetch_add(&cnt[b], 1, __ATOMIC_RELEASE, __HIP_MEMORY_SCOPE_AGENT);
        return;
    }

    if (bx < 260) {
        // ================== vpart producer ==================
        float* xred = reinterpret_cast<float*>(smem);   // [0:128) rg0, [128:256) rg1, [256:384) xsum
        const int idx = bx - 4;
        const int b = idx >> 6, i = idx & 63;
        const size_t base = ((size_t)b * SS + 64 + (size_t)i * 63) * EE;
        const int col = tid & 127, rg = tid >> 7;
        float s = 0.f;
        for (int r = rg; r < 63; r += 2)
            s += x[base + (size_t)r * EE + col];
        xred[rg * 128 + col] = s;
        __syncthreads();
        if (tid < 128) xred[256 + tid] = xred[tid] + xred[128 + tid];
        __syncthreads();
        if (tid < 128) {
            float a = 0.f;
            #pragma unroll 8
            for (int e = 0; e < 128; e += 4) {
                float4 wv = *reinterpret_cast<const float4*>(Wv + (size_t)tid * EE + e);
                a = fmaf(xred[256 + e + 0], wv.x, a);
                a = fmaf(xred[256 + e + 1], wv.y, a);
                a = fmaf(xred[256 + e + 2], wv.z, a);
                a = fmaf(xred[256 + e + 3], wv.w, a);
            }
            vpart[((size_t)b * 64 + i) * 128 + tid] = a;
        }
        __threadfence();
        __syncthreads();
        if (tid == 0)
            __hip_atomic_fetch_add(&cnt[b], 1, __ATOMIC_RELEASE, __HIP_MEMORY_SCOPE_AGENT);
        return;
    }

    // ================== consumer: 4 waves x 16 rows ==================
    const int cb = bx - 260;
    const int b = cb >> 6;
    const int s0 = (cb & 63) * 64;
    const int l = tid & 63, w = tid >> 6;
    const int lm = l & 15, lg = l >> 4;
    const int srow = s0 + w * 16;

    float (*Plds)[68] = reinterpret_cast<float (*)[68]>(smem);        // 64 rows
    float* vsred = reinterpret_cast<float*>(smem + 17408);            // [2][128]
    float* vsS   = reinterpret_cast<float*>(smem + 18432);            // [128]

    // x A-frags first (only dependence: x)
    bf16x8 xh[4], xl[4];
    const float* xrow = x + ((size_t)b * SS + srow + lm) * EE + lg * 8;
    #pragma unroll
    for (int kt = 0; kt < 4; ++kt)
        split8(xrow + kt * 32, xh[kt], xl[kt]);

    // spin until this batch's producers are done (wave 0 polls, rest wait)
    if (w == 0) {
        while (__hip_atomic_load(&cnt[b], __ATOMIC_RELAXED, __HIP_MEMORY_SCOPE_AGENT) < CNT_TARGET)
            __builtin_amdgcn_s_sleep(2);
        (void)__hip_atomic_load(&cnt[b], __ATOMIC_ACQUIRE, __HIP_MEMORY_SCOPE_AGENT);
    }
    __syncthreads();

    // block-shared vsum: thread owns (col, half), fixed-order reduce
    {
        const int col = tid & 127, half = tid >> 7;
        float s = 0.f;
        #pragma unroll 8
        for (int i = half * 32; i < half * 32 + 32; ++i)
            s += vpart[(size_t)b * 8192 + (size_t)i * 128 + col];
        vsred[half * 128 + col] = s;
    }
    __syncthreads();
    if (tid < 128) vsS[tid] = vsred[tid] + vsred[128 + tid];
    __syncthreads();

    // S = x @ Mt : 4 col-tiles x (4 k-tiles x 3 split-mfma)
    f32x4 sa[4];
    const short* mh_base = (const short*)Mth + (size_t)b * 8192 + lg * 8;
    const short* ml_base = (const short*)Mtl + (size_t)b * 8192 + lg * 8;
    #pragma unroll
    for (int ct = 0; ct < 4; ++ct) {
        f32x4 a = {0.f, 0.f, 0.f, 0.f};
        const size_t trow = (size_t)(ct * 16 + lm) * 128;
        #pragma unroll
        for (int kt = 0; kt < 4; ++kt) {
            bf16x8 mh = *reinterpret_cast<const bf16x8*>(mh_base + trow + kt * 32);
            bf16x8 ml = *reinterpret_cast<const bf16x8*>(ml_base + trow + kt * 32);
            a = __builtin_amdgcn_mfma_f32_16x16x32_bf16(xh[kt], mh, a, 0, 0, 0);
            a = __builtin_amdgcn_mfma_f32_16x16x32_bf16(xl[kt], mh, a, 0, 0, 0);
            a = __builtin_amdgcn_mfma_f32_16x16x32_bf16(xh[kt], ml, a, 0, 0, 0);
        }
        sa[ct] = a;
    }

    // softmax over 4096 cols: 64 real + 4032 exact zeros
    float e[4], iz[4];
    #pragma unroll
    for (int r = 0; r < 4; ++r) {
        float m = fmaxf(fmaxf(sa[0][r], sa[1][r]), fmaxf(sa[2][r], sa[3][r]));
        #pragma unroll
        for (int o = 1; o < 16; o <<= 1) m = fmaxf(m, __shfl_xor(m, o));
        m = fmaxf(m, 0.f);
        float w0 = __expf(sa[0][r] - m), w1 = __expf(sa[1][r] - m);
        float w2 = __expf(sa[2][r] - m), w3 = __expf(sa[3][r] - m);
        sa[0][r] = w0; sa[1][r] = w1; sa[2][r] = w2; sa[3][r] = w3;
        float z = (w0 + w1) + (w2 + w3);
        #pragma unroll
        for (int o = 1; o < 16; o <<= 1) z += __shfl_xor(z, o);
        e[r] = __expf(-m);
        z += 4032.f * e[r];
        iz[r] = 1.f / z;
    }

    // P relayout (per-wave region of Plds): C/D layout -> A-frag layout
    #pragma unroll
    for (int ct = 0; ct < 4; ++ct)
        #pragma unroll
        for (int r = 0; r < 4; ++r)
            Plds[w * 16 + lg * 4 + r][ct * 16 + lm] = sa[ct][r];
    bf16x8 pf[2];
    #pragma unroll
    for (int kt2 = 0; kt2 < 2; ++kt2) {
        const float* pr = &Plds[w * 16 + lm][kt2 * 32 + lg * 8];
        #pragma unroll
        for (int i = 0; i < 8; ++i) pf[kt2][i] = (short)f2bf(pr[i]);
    }

    // PV + vsum term + normalize + store
    const short* vb = (const short*)Vt + (size_t)b * 8192 + lg * 8;
    const size_t obase = ((size_t)b * SS + srow) * EE;
    #pragma unroll
    for (int ct = 0; ct < 8; ++ct) {
        const int col = ct * 16 + lm;
        bf16x8 v0 = *reinterpret_cast<const bf16x8*>(vb + (size_t)col * 64);
        bf16x8 v1 = *reinterpret_cast<const bf16x8*>(vb + (size_t)col * 64 + 32);
        f32x4 a = {0.f, 0.f, 0.f, 0.f};
        a = __builtin_amdgcn_mfma_f32_16x16x32_bf16(pf[0], v0, a, 0, 0, 0);
        a = __builtin_amdgcn_mfma_f32_16x16x32_bf16(pf[1], v1, a, 0, 0, 0);
        const float vs = vsS[col];
        #pragma unroll
        for (int r = 0; r < 4; ++r)
            out[obase + (size_t)(lg * 4 + r) * EE + col] = (a[r] + e[r] * vs) * iz[r];
    }
}

// ---------------------------------------------------------------------------
extern "C" void kernel_launch(void* const* d_in, const int* in_sizes, int n_in,
                              void* d_out, int out_size, void* d_ws, size_t ws_size,
                              hipStream_t stream)
{
    const float* x  = (const float*)d_in[0];
    const float* Wk = (const float*)d_in[1];
    const float* Wq = (const float*)d_in[2];
    const float* Wv = (const float*)d_in[3];
    float* out = (float*)d_out;

    int* cnt = (int*)d_ws;                                  // 4 ints (+pad to 256B)
    float* vpart = (float*)((char*)d_ws + 256);             // 4*64*128 f32
    unsigned short* Mth = (unsigned short*)(vpart + 32768); // 4*64*128 bf16
    unsigned short* Mtl = Mth + 32768;                      // 4*64*128 bf16
    unsigned short* Vt  = Mtl + 32768;                      // 4*128*64 bf16

    hipMemsetAsync(cnt, 0, 4 * sizeof(int), stream);
    fused_all<<<516, 256, 0, stream>>>(x, Wk, Wq, Wv, cnt, vpart, Mth, Mtl, Vt, out);
}

// Round 9
// 34.867 us; speedup vs baseline: 2.2137x; 2.2137x over previous
//
#include <hip/hip_runtime.h>

#define BB 4
#define SS 4096
#define EE 128

typedef __attribute__((ext_vector_type(8))) short bf16x8;
typedef __attribute__((ext_vector_type(4))) float f32x4;

__device__ __forceinline__ unsigned short f2bf(float f) {
    unsigned u = __float_as_uint(f);
    u = (u + 0x7FFFu + ((u >> 16) & 1u)) >> 16;
    return (unsigned short)u;
}
__device__ __forceinline__ float bf2f(unsigned short h) {
    return __uint_as_float(((unsigned)h) << 16);
}
__device__ __forceinline__ void split8(const float* p, bf16x8& h, bf16x8& l) {
    float4 v0 = *reinterpret_cast<const float4*>(p);
    float4 v1 = *reinterpret_cast<const float4*>(p + 4);
    float f[8] = {v0.x, v0.y, v0.z, v0.w, v1.x, v1.y, v1.z, v1.w};
    #pragma unroll
    for (int i = 0; i < 8; ++i) {
        unsigned short hb = f2bf(f[i]);
        h[i] = (short)hb;
        l[i] = (short)f2bf(f[i] - bf2f(hb));
    }
}
__device__ __forceinline__ void split8r(const float* f, bf16x8& h, bf16x8& l) {
    #pragma unroll
    for (int i = 0; i < 8; ++i) {
        unsigned short hb = f2bf(f[i]);
        h[i] = (short)hb;
        l[i] = (short)f2bf(f[i] - bf2f(hb));
    }
}
// 3-product split-bf16 MFMA: ~f32 accuracy (drops lo*lo)
__device__ __forceinline__ f32x4 mfma3(bf16x8 ah, bf16x8 al, bf16x8 bh, bf16x8 bl, f32x4 c) {
    c = __builtin_amdgcn_mfma_f32_16x16x32_bf16(ah, bh, c, 0, 0, 0);
    c = __builtin_amdgcn_mfma_f32_16x16x32_bf16(al, bh, c, 0, 0, 0);
    c = __builtin_amdgcn_mfma_f32_16x16x32_bf16(ah, bl, c, 0, 0, 0);
    return c;
}

// ---------------------------------------------------------------------------
// K1 prep: blocks [0,256): vpart producer: idx=bx, b=idx>>6, i=idx&63:
//            vpart[b][i][:] = (colsum of x[b, 64+63i .. +63, :]) @ Wv^T
//          blocks [256,260): special producer, batch b=bx-256, 4 waves,
//            wave w owns t-strip [16w,16w+16), all-MFMA (r8 path, no LDS
//            transpose staging):
//            K:  ksub[t][j] = (t<=j) ? x64[t].Wk[j] : 0     (LDS f32)
//            Mt: Mth/Mtl[t][e] = bf16hi/lo( sum_j ksub[t][j]*Wq[j][e] )
//            V:  Vt[v][t] = bf16( x64[t].Wv[v] )
// ---------------------------------------------------------------------------
__global__ __launch_bounds__(256, 2)
void prep(const float* __restrict__ x, const float* __restrict__ Wk,
          const float* __restrict__ Wq, const float* __restrict__ Wv,
          unsigned short* __restrict__ Vt,
          unsigned short* __restrict__ Mth, unsigned short* __restrict__ Mtl,
          float* __restrict__ vpart)
{
    __shared__ float ksub[64][68];           // special: masked K [t][j]; vpart: xred overlay
    const int tid = threadIdx.x;
    const int bx = blockIdx.x;

    if (bx < 256) {
        // ================== vpart producer ==================
        float* xred = &ksub[0][0];   // [0:128) rg0, [128:256) rg1, [256:384) xsum
        const int b = bx >> 6, i = bx & 63;
        const size_t base = ((size_t)b * SS + 64 + (size_t)i * 63) * EE;
        const int col = tid & 127, rg = tid >> 7;
        float s = 0.f;
        for (int r = rg; r < 63; r += 2)
            s += x[base + (size_t)r * EE + col];
        xred[rg * 128 + col] = s;
        __syncthreads();
        if (tid < 128) xred[256 + tid] = xred[tid] + xred[128 + tid];
        __syncthreads();
        if (tid < 128) {
            float a = 0.f;
            #pragma unroll 8
            for (int e = 0; e < 128; e += 4) {
                float4 wv = *reinterpret_cast<const float4*>(Wv + (size_t)tid * EE + e);
                a = fmaf(xred[256 + e + 0], wv.x, a);
                a = fmaf(xred[256 + e + 1], wv.y, a);
                a = fmaf(xred[256 + e + 2], wv.z, a);
                a = fmaf(xred[256 + e + 3], wv.w, a);
            }
            vpart[((size_t)b * 64 + i) * 128 + tid] = a;
        }
        return;
    }

    // ================== special producer (batch b) ==================
    const int b = bx - 256;
    const int l = tid & 63, w = tid >> 6;
    const int lm = l & 15, lg = l >> 4;
    const int t0 = w * 16;

    // WqT A-frag raw loads: wq_raw[eti][kt2][i] = Wq[kt2*32+lg*8+i][32w+16*eti+lm]
    float wq_raw[2][2][8];
    #pragma unroll
    for (int eti = 0; eti < 2; ++eti)
        #pragma unroll
        for (int kt2 = 0; kt2 < 2; ++kt2) {
            const int e = 32 * w + 16 * eti + lm;
            const int j0 = kt2 * 32 + lg * 8;
            #pragma unroll
            for (int i = 0; i < 8; ++i)
                wq_raw[eti][kt2][i] = Wq[(size_t)(j0 + i) * EE + e];
        }

    // x A-frags for this t-strip (shared by K and V GEMMs)
    bf16x8 xh[4], xl[4];
    const float* xrow = x + ((size_t)b * SS + t0 + lm) * EE + lg * 8;
    #pragma unroll
    for (int kt = 0; kt < 4; ++kt)
        split8(xrow + kt * 32, xh[kt], xl[kt]);

    // K-GEMM: K[t][j] = x64[t].Wk[j]; mask t<=j; write own strip to ksub
    #pragma unroll
    for (int jt = 0; jt < 4; ++jt) {
        f32x4 a = {0.f, 0.f, 0.f, 0.f};
        const float* wkr = Wk + (size_t)(jt * 16 + lm) * EE + lg * 8;
        #pragma unroll
        for (int kt = 0; kt < 4; ++kt) {
            bf16x8 bh, bl;
            split8(wkr + kt * 32, bh, bl);
            a = mfma3(xh[kt], xl[kt], bh, bl, a);
        }
        const int j = jt * 16 + lm;
        #pragma unroll
        for (int r = 0; r < 4; ++r) {
            const int t = t0 + lg * 4 + r;
            ksub[t][j] = (t <= j) ? a[r] : 0.f;
        }
    }
    __syncthreads();                       // full ksub visible

    // Mt-GEMM: D[e][t] = sum_j Wq[j][e]*ksub[t][j]; wave owns e in [32w,32w+32)
    bf16x8 ah[2][2], al[2][2];
    #pragma unroll
    for (int eti = 0; eti < 2; ++eti)
        #pragma unroll
        for (int kt2 = 0; kt2 < 2; ++kt2)
            split8r(&wq_raw[eti][kt2][0], ah[eti][kt2], al[eti][kt2]);
    #pragma unroll
    for (int eti = 0; eti < 2; ++eti)
        #pragma unroll
        for (int tt = 0; tt < 4; ++tt) {
            f32x4 a = {0.f, 0.f, 0.f, 0.f};
            #pragma unroll
            for (int kt2 = 0; kt2 < 2; ++kt2) {
                bf16x8 bh, bl;
                split8(&ksub[tt * 16 + lm][kt2 * 32 + lg * 8], bh, bl);
                a = mfma3(ah[eti][kt2], al[eti][kt2], bh, bl, a);
            }
            const int t = tt * 16 + lm;
            const int e0 = 32 * w + 16 * eti + lg * 4;
            unsigned short h0 = f2bf(a[0]), h1 = f2bf(a[1]);
            unsigned short h2 = f2bf(a[2]), h3 = f2bf(a[3]);
            ushort4 hv = make_ushort4(h0, h1, h2, h3);
            ushort4 lv = make_ushort4(f2bf(a[0] - bf2f(h0)), f2bf(a[1] - bf2f(h1)),
                                      f2bf(a[2] - bf2f(h2)), f2bf(a[3] - bf2f(h3)));
            const size_t off = (size_t)b * 8192 + (size_t)t * 128 + e0;
            *reinterpret_cast<ushort4*>(Mth + off) = hv;
            *reinterpret_cast<ushort4*>(Mtl + off) = lv;
        }

    // V-GEMM: V[t][v] = x64[t].Wv[v]; store Vt[v][t] bf16
    #pragma unroll
    for (int vt = 0; vt < 8; ++vt) {
        f32x4 a = {0.f, 0.f, 0.f, 0.f};
        const float* wvr = Wv + (size_t)(vt * 16 + lm) * EE + lg * 8;
        #pragma unroll
        for (int kt = 0; kt < 4; ++kt) {
            bf16x8 bh, bl;
            split8(wvr + kt * 32, bh, bl);
            a = mfma3(xh[kt], xl[kt], bh, bl, a);
        }
        const int v = vt * 16 + lm;
        ushort4 pk = make_ushort4(f2bf(a[0]), f2bf(a[1]), f2bf(a[2]), f2bf(a[3]));
        *reinterpret_cast<ushort4*>(Vt + (size_t)b * 8192 + (size_t)v * 64 + t0 + lg * 4) = pk;
    }
}

// ---------------------------------------------------------------------------
// K2 attn_main: 256 blocks x 4 waves; block handles 64 rows of batch b.
// Block-shared vsum (fixed-order), S = x@Mt (split MFMA), softmax with
// 4032 zero-column term, P relayout via LDS, PV MFMA + vsum term + store.
// ---------------------------------------------------------------------------
__global__ __launch_bounds__(256, 2)
void attn_main(const float* __restrict__ x, const short* __restrict__ Mth,
               const short* __restrict__ Mtl, const short* __restrict__ Vt,
               const float* __restrict__ vpart, float* __restrict__ out)
{
    __shared__ float Plds[64][68];
    __shared__ float vsred[2][128];
    __shared__ float vsS[128];
    const int tid = threadIdx.x;
    const int bx = blockIdx.x;
    const int b = bx >> 6;
    const int s0 = (bx & 63) * 64;
    const int l = tid & 63, w = tid >> 6;
    const int lm = l & 15, lg = l >> 4;
    const int srow = s0 + w * 16;

    // x A-frags
    bf16x8 xh[4], xl[4];
    const float* xrow = x + ((size_t)b * SS + srow + lm) * EE + lg * 8;
    #pragma unroll
    for (int kt = 0; kt < 4; ++kt)
        split8(xrow + kt * 32, xh[kt], xl[kt]);

    // block-shared vsum: thread owns (col, half), fixed-order reduce
    {
        const int col = tid & 127, half = tid >> 7;
        float s = 0.f;
        #pragma unroll 8
        for (int i = half * 32; i < half * 32 + 32; ++i)
            s += vpart[(size_t)b * 8192 + (size_t)i * 128 + col];
        vsred[half][col] = s;
    }
    __syncthreads();
    if (tid < 128) vsS[tid] = vsred[0][tid] + vsred[1][tid];
    __syncthreads();

    // S = x @ Mt : 4 col-tiles x (4 k-tiles x 3 split-mfma)
    f32x4 sa[4];
    const short* mh_base = Mth + (size_t)b * 8192 + lg * 8;
    const short* ml_base = Mtl + (size_t)b * 8192 + lg * 8;
    #pragma unroll
    for (int ct = 0; ct < 4; ++ct) {
        f32x4 a = {0.f, 0.f, 0.f, 0.f};
        const size_t trow = (size_t)(ct * 16 + lm) * 128;
        #pragma unroll
        for (int kt = 0; kt < 4; ++kt) {
            bf16x8 mh = *reinterpret_cast<const bf16x8*>(mh_base + trow + kt * 32);
            bf16x8 ml = *reinterpret_cast<const bf16x8*>(ml_base + trow + kt * 32);
            a = __builtin_amdgcn_mfma_f32_16x16x32_bf16(xh[kt], mh, a, 0, 0, 0);
            a = __builtin_amdgcn_mfma_f32_16x16x32_bf16(xl[kt], mh, a, 0, 0, 0);
            a = __builtin_amdgcn_mfma_f32_16x16x32_bf16(xh[kt], ml, a, 0, 0, 0);
        }
        sa[ct] = a;
    }

    // softmax over 4096 cols: 64 real + 4032 exact zeros
    float e[4], iz[4];
    #pragma unroll
    for (int r = 0; r < 4; ++r) {
        float m = fmaxf(fmaxf(sa[0][r], sa[1][r]), fmaxf(sa[2][r], sa[3][r]));
        #pragma unroll
        for (int o = 1; o < 16; o <<= 1) m = fmaxf(m, __shfl_xor(m, o));
        m = fmaxf(m, 0.f);
        float w0 = __expf(sa[0][r] - m), w1 = __expf(sa[1][r] - m);
        float w2 = __expf(sa[2][r] - m), w3 = __expf(sa[3][r] - m);
        sa[0][r] = w0; sa[1][r] = w1; sa[2][r] = w2; sa[3][r] = w3;
        float z = (w0 + w1) + (w2 + w3);
        #pragma unroll
        for (int o = 1; o < 16; o <<= 1) z += __shfl_xor(z, o);
        e[r] = __expf(-m);
        z += 4032.f * e[r];
        iz[r] = 1.f / z;
    }

    // P relayout (per-wave rows of Plds): C/D layout -> A-frag layout
    #pragma unroll
    for (int ct = 0; ct < 4; ++ct)
        #pragma unroll
        for (int r = 0; r < 4; ++r)
            Plds[w * 16 + lg * 4 + r][ct * 16 + lm] = sa[ct][r];
    bf16x8 pf[2];
    #pragma unroll
    for (int kt2 = 0; kt2 < 2; ++kt2) {
        const float* pr = &Plds[w * 16 + lm][kt2 * 32 + lg * 8];
        #pragma unroll
        for (int i = 0; i < 8; ++i) pf[kt2][i] = (short)f2bf(pr[i]);
    }

    // PV + vsum term + normalize + store
    const short* vb = Vt + (size_t)b * 8192 + lg * 8;
    const size_t obase = ((size_t)b * SS + srow) * EE;
    #pragma unroll
    for (int ct = 0; ct < 8; ++ct) {
        const int col = ct * 16 + lm;
        bf16x8 v0 = *reinterpret_cast<const bf16x8*>(vb + (size_t)col * 64);
        bf16x8 v1 = *reinterpret_cast<const bf16x8*>(vb + (size_t)col * 64 + 32);
        f32x4 a = {0.f, 0.f, 0.f, 0.f};
        a = __builtin_amdgcn_mfma_f32_16x16x32_bf16(pf[0], v0, a, 0, 0, 0);
        a = __builtin_amdgcn_mfma_f32_16x16x32_bf16(pf[1], v1, a, 0, 0, 0);
        const float vs = vsS[col];
        #pragma unroll
        for (int r = 0; r < 4; ++r)
            out[obase + (size_t)(lg * 4 + r) * EE + col] = (a[r] + e[r] * vs) * iz[r];
    }
}

// ---------------------------------------------------------------------------
extern "C" void kernel_launch(void* const* d_in, const int* in_sizes, int n_in,
                              void* d_out, int out_size, void* d_ws, size_t ws_size,
                              hipStream_t stream)
{
    const float* x  = (const float*)d_in[0];
    const float* Wk = (const float*)d_in[1];
    const float* Wq = (const float*)d_in[2];
    const float* Wv = (const float*)d_in[3];
    float* out = (float*)d_out;

    float* vpart = (float*)d_ws;                            // 4*64*128 f32
    unsigned short* Mth = (unsigned short*)(vpart + 32768); // 4*64*128 bf16
    unsigned short* Mtl = Mth + 32768;                      // 4*64*128 bf16
    unsigned short* Vt  = Mtl + 32768;                      // 4*128*64 bf16

    prep<<<260, 256, 0, stream>>>(x, Wk, Wq, Wv, Vt, Mth, Mtl, vpart);
    attn_main<<<256, 256, 0, stream>>>(
        x, (const short*)Mth, (const short*)Mtl, (const short*)Vt, vpart, out);
}